// Round 5
// baseline (80.871 us; speedup 1.0000x reference)
//
#include <hip/hip_runtime.h>

// out[b,o] = radius * (1/sqrt(K)) * sum_k cos(c*(w[o,k]-x[b,k])),  c = 2*pi/8
//          = radius * (1/sqrt(K)) * sum_k [cos(cx)cos(cw) + sin(cx)sin(cw)]
// B=2048, K=32768, O=10.
// Round 5: occupancy push. BROWS 4->2 cuts live VGPRs (~128 -> ~85) for
// 6 waves/SIMD; grid 1024 -> 2048 blocks. w stays (cos,sin) f16 pairs,
// inner op v_dot2_f32_f16, f32 accum.

typedef _Float16 half2_t __attribute__((ext_vector_type(2)));

#define K_DIM 32768
#define B_DIM 2048
#define O_DIM 10
#define BROWS 2                 // x rows per block
#define KCH 2                   // K chunks per row-group
#define KC_LEN (K_DIM / KCH)    // 16384
#define THREADS 256
#define QUADS (KC_LEN / (THREADS * 4))   // 16 iterations per thread
#define KQ (K_DIM / 4)          // row stride in float4 / half2x4 units
#define INV_SQRT_K 0.005524271728019903f

// hardware v_sin/v_cos take REVOLUTIONS: sin(2*pi*r). c*x radians -> r = x/8.

__device__ __forceinline__ half2_t pack_cs(float c, float s) {
    return __builtin_bit_cast(half2_t, __builtin_amdgcn_cvt_pkrtz(c, s));
}

__device__ __forceinline__ float dot2(half2_t a, half2_t b, float acc) {
#if __has_builtin(__builtin_amdgcn_fdot2)
    return __builtin_amdgcn_fdot2(a, b, acc, false);
#else
    return acc + (float)a.x * (float)b.x + (float)a.y * (float)b.y;
#endif
}

__global__ void wtrig_kernel(const float* __restrict__ w,
                             half2_t* __restrict__ wp) {
    int i = blockIdx.x * blockDim.x + threadIdx.x;   // exact: 1280*256 = 327680
    float r = w[i] * 0.125f;
    wp[i] = pack_cs(__builtin_amdgcn_cosf(r), __builtin_amdgcn_sinf(r));
}

__global__ __launch_bounds__(THREADS) void gsim_main(
        const float* __restrict__ x,
        const half2_t* __restrict__ wp,
        float* __restrict__ part) {
    const int bid = blockIdx.x;
    const int rg = bid >> 1;          // row group
    const int kc = bid & 1;           // k chunk
    const int r0 = rg * BROWS;
    const int t = threadIdx.x;

    float acc[BROWS][O_DIM];
    #pragma unroll
    for (int r = 0; r < BROWS; ++r)
        #pragma unroll
        for (int o = 0; o < O_DIM; ++o) acc[r][o] = 0.f;

    const float4* xq = (const float4*)x;
    const float4* wq = (const float4*)wp;   // one float4 = 4 half2 = 4 k of (c,s)

    const int q0 = kc * (KC_LEN / 4) + t;   // quad index at iteration 0
    const int xbase = r0 * KQ + q0;

    // pipeline prologue: iteration 0's x quads
    float4 xb[BROWS];
    #pragma unroll
    for (int r = 0; r < BROWS; ++r) xb[r] = xq[xbase + r * KQ];

    #pragma unroll 1
    for (int i = 0; i < QUADS; ++i) {
        const int wqi = q0 + i * THREADS;

        // issue all w loads first; their latency hides under the trig below
        float4 wv[O_DIM];
        #pragma unroll
        for (int o = 0; o < O_DIM; ++o) wv[o] = wq[o * KQ + wqi];

        // trig + f16 pack (x-prefetch waitcnt lands here, vmcnt allows w in flight)
        half2_t pk[BROWS][4];
        #pragma unroll
        for (int r = 0; r < BROWS; ++r) {
            const float* xp = (const float*)&xb[r];
            #pragma unroll
            for (int j = 0; j < 4; ++j) {
                float rr = xp[j] * 0.125f;      // revolutions
                pk[r][j] = pack_cs(__builtin_amdgcn_cosf(rr),
                                   __builtin_amdgcn_sinf(rr));
            }
        }

        // issue next iteration's x loads; in flight across the dot2 loop
        if (i + 1 < QUADS) {
            const int nb = xbase + (i + 1) * THREADS;
            #pragma unroll
            for (int r = 0; r < BROWS; ++r) xb[r] = xq[nb + r * KQ];
        }

        // accumulate: one v_dot2_f32_f16 per (r,o,k)
        #pragma unroll
        for (int o = 0; o < O_DIM; ++o) {
            const half2_t* wh = (const half2_t*)&wv[o];
            #pragma unroll
            for (int r = 0; r < BROWS; ++r)
                #pragma unroll
                for (int j = 0; j < 4; ++j)
                    acc[r][o] = dot2(pk[r][j], wh[j], acc[r][o]);
        }
    }

    // 64-lane butterfly reduction per accumulator
    #pragma unroll
    for (int r = 0; r < BROWS; ++r)
        #pragma unroll
        for (int o = 0; o < O_DIM; ++o) {
            float v = acc[r][o];
            #pragma unroll
            for (int off = 32; off > 0; off >>= 1)
                v += __shfl_xor(v, off, 64);
            acc[r][o] = v;
        }

    __shared__ float red[THREADS / 64][BROWS * O_DIM];
    const int wave = t >> 6;
    const int lane = t & 63;
    if (lane == 0) {
        #pragma unroll
        for (int r = 0; r < BROWS; ++r)
            #pragma unroll
            for (int o = 0; o < O_DIM; ++o)
                red[wave][r * O_DIM + o] = acc[r][o];
    }
    __syncthreads();
    if (t < BROWS * O_DIM) {
        float v = red[0][t] + red[1][t] + red[2][t] + red[3][t];
        part[(size_t)kc * (B_DIM * O_DIM)
             + (size_t)(r0 + t / O_DIM) * O_DIM + (t % O_DIM)] = v;
    }
}

__global__ void finalize_kernel(const float* __restrict__ part,
                                const float* __restrict__ radius,
                                float* __restrict__ out) {
    int i = blockIdx.x * blockDim.x + threadIdx.x;
    if (i < B_DIM * O_DIM) {
        float v = part[i] + part[(size_t)B_DIM * O_DIM + i];
        out[i] = v * radius[0] * INV_SQRT_K;
    }
}

extern "C" void kernel_launch(void* const* d_in, const int* in_sizes, int n_in,
                              void* d_out, int out_size, void* d_ws, size_t ws_size,
                              hipStream_t stream) {
    const float* x      = (const float*)d_in[0];
    const float* w      = (const float*)d_in[1];
    const float* radius = (const float*)d_in[2];
    float* out = (float*)d_out;

    // workspace: wp[10][32768] half2 (1.31 MB) | part[2][2048][10] f32
    half2_t* wpd = (half2_t*)d_ws;
    float* part  = (float*)(wpd + (size_t)O_DIM * K_DIM);

    hipLaunchKernelGGL(wtrig_kernel, dim3((O_DIM * K_DIM) / THREADS), dim3(THREADS),
                       0, stream, w, wpd);
    hipLaunchKernelGGL(gsim_main, dim3((B_DIM / BROWS) * KCH), dim3(THREADS),
                       0, stream, x, wpd, part);
    hipLaunchKernelGGL(finalize_kernel, dim3((B_DIM * O_DIM + THREADS - 1) / THREADS),
                       dim3(THREADS), 0, stream, part, radius, out);
}

// Round 6
// 60.583 us; speedup vs baseline: 1.3349x; 1.3349x over previous
//
#include <hip/hip_runtime.h>

// out[b,o] = radius * (1/sqrt(K)) * sum_k cos(c*(w[o,k]-x[b,k])),  c = 2*pi/8
//          = radius * (1/sqrt(K)) * sum_k [cos(cx)cos(cw) + sin(cx)sin(cw)]
// B=2048, K=32768, O=10.
// Round 6: MFMA formulation. K'=2K with (cos,sin) interleaved; A[b,k'] from
// on-the-fly x trig (f16), B[o,k'] from precomputed f16 table laid out in
// MFMA B-fragment order. mfma_f32_16x16x32_f16, f32 accum. Wave owns a
// 16-row x 16-col tile over a K-chunk; partials summed by finalize.

typedef _Float16 half2_t __attribute__((ext_vector_type(2)));
typedef _Float16 half8_t __attribute__((ext_vector_type(8)));
typedef float f32x4 __attribute__((ext_vector_type(4)));

#define K_DIM 32768
#define B_DIM 2048
#define O_DIM 10
#define NWIN 2048               // windows; one window = 16 x-ks = 32 K'-elems
#define KCH 64                  // K-chunks
#define WPC (NWIN / KCH)        // 32 windows per chunk
#define MTILES (B_DIM / 64)     // 32 blocks of 64 rows
#define THREADS 256
#define INV_SQRT_K 0.005524271728019903f

// hardware v_sin/v_cos take REVOLUTIONS: sin(2*pi*r). c*x radians -> r = x/8.

__device__ __forceinline__ half2_t pack_cs(float c, float s) {
    return __builtin_bit_cast(half2_t, __builtin_amdgcn_cvt_pkrtz(c, s));
}

// B-fragment table: for window t, lane l: 16 bytes = (cos,sin) f16 pairs of
// w[o = l&15][k = t*16 + (l>>4)*4 + 0..3]; o >= 10 -> zeros.
__global__ void wtab_kernel(const float* __restrict__ w,
                            uint4* __restrict__ wtab) {
    int gid = blockIdx.x * THREADS + threadIdx.x;    // 2048*64 = 131072 exact
    int t = gid >> 6, l = gid & 63;
    int o = l & 15, kg = l >> 4;
    int k = t * 16 + kg * 4;
    uint4 v; v.x = v.y = v.z = v.w = 0u;
    if (o < O_DIM) {
        const float4 wv = *(const float4*)(w + (size_t)o * K_DIM + k);
        const float* wp = (const float*)&wv;
        unsigned u[4];
        #pragma unroll
        for (int j = 0; j < 4; ++j) {
            float rr = wp[j] * 0.125f;
            u[j] = __builtin_bit_cast(unsigned,
                       pack_cs(__builtin_amdgcn_cosf(rr),
                               __builtin_amdgcn_sinf(rr)));
        }
        v.x = u[0]; v.y = u[1]; v.z = u[2]; v.w = u[3];
    }
    wtab[gid] = v;
}

__global__ __launch_bounds__(THREADS) void gsim_mfma(
        const float* __restrict__ x,
        const uint4* __restrict__ wtab,
        float* __restrict__ part) {
    const int bid = blockIdx.x;
    const int mt = bid & (MTILES - 1);   // m-tile (fast) -> same-kc blocks adjacent
    const int kc = bid >> 5;             // k-chunk
    const int t = threadIdx.x;
    const int wave = t >> 6, lane = t & 63;
    const int o = lane & 15, kg = lane >> 4;

    // A-side: lane reads row (mt*64 + wave*16 + o), 4 floats at k-window
    const int row = mt * 64 + wave * 16 + o;
    const int t0 = kc * WPC;
    const float4* xp = (const float4*)x + ((size_t)row * (K_DIM / 4) + t0 * 4 + kg);
    const uint4* bp = wtab + (size_t)t0 * 64 + lane;

    f32x4 acc = {0.f, 0.f, 0.f, 0.f};
    float4 xc = xp[0];
    uint4  bc = bp[0];

    #pragma unroll 2
    for (int i = 0; i < WPC; ++i) {
        const int ni = (i + 1 < WPC) ? (i + 1) : i;   // last iter: harmless reload
        float4 xn = xp[ni * 4];
        uint4  bn = bp[ni * 64];

        // A fragment: 4 x floats -> (cos,sin) f16 pairs -> 8 f16
        const float* xf = (const float*)&xc;
        uint4 au;
        {
            unsigned u[4];
            #pragma unroll
            for (int j = 0; j < 4; ++j) {
                float rr = xf[j] * 0.125f;            // revolutions
                u[j] = __builtin_bit_cast(unsigned,
                           pack_cs(__builtin_amdgcn_cosf(rr),
                                   __builtin_amdgcn_sinf(rr)));
            }
            au.x = u[0]; au.y = u[1]; au.z = u[2]; au.w = u[3];
        }
        half8_t a = __builtin_bit_cast(half8_t, au);
        half8_t b = __builtin_bit_cast(half8_t, bc);
        acc = __builtin_amdgcn_mfma_f32_16x16x32_f16(a, b, acc, 0, 0, 0);

        xc = xn; bc = bn;
    }

    // C/D layout: col = lane&15, row_in_tile = (lane>>4)*4 + reg  [m89]
    const int rbase = mt * 64 + wave * 16 + kg * 4;
    float* pp = part + ((size_t)kc * B_DIM + rbase) * 16 + o;
    #pragma unroll
    for (int reg = 0; reg < 4; ++reg)
        pp[(size_t)reg * 16] = acc[reg];
}

__global__ void finalize_kernel(const float* __restrict__ part,
                                const float* __restrict__ radius,
                                float* __restrict__ out) {
    int gid = blockIdx.x * THREADS + threadIdx.x;    // 2048*16 = 32768 exact
    int b = gid >> 4, o = gid & 15;
    if (o >= O_DIM) return;
    float s = 0.f;
    #pragma unroll 8
    for (int kc = 0; kc < KCH; ++kc)
        s += part[(size_t)kc * (B_DIM * 16) + gid];
    out[(size_t)b * O_DIM + o] = s * radius[0] * INV_SQRT_K;
}

extern "C" void kernel_launch(void* const* d_in, const int* in_sizes, int n_in,
                              void* d_out, int out_size, void* d_ws, size_t ws_size,
                              hipStream_t stream) {
    const float* x      = (const float*)d_in[0];
    const float* w      = (const float*)d_in[1];
    const float* radius = (const float*)d_in[2];
    float* out = (float*)d_out;

    // ws: wtab[2048][64] uint4 (2 MB) | part[64][2048][16] f32 (8 MB)
    uint4* wtab = (uint4*)d_ws;
    float* part = (float*)((char*)d_ws + (size_t)NWIN * 64 * 16);

    hipLaunchKernelGGL(wtab_kernel, dim3(NWIN * 64 / THREADS), dim3(THREADS),
                       0, stream, w, wtab);
    hipLaunchKernelGGL(gsim_mfma, dim3(MTILES * KCH), dim3(THREADS),
                       0, stream, x, wtab, part);
    hipLaunchKernelGGL(finalize_kernel, dim3(B_DIM * 16 / THREADS), dim3(THREADS),
                       0, stream, part, radius, out);
}

// Round 7
// 60.263 us; speedup vs baseline: 1.3420x; 1.0053x over previous
//
#include <hip/hip_runtime.h>

// out[b,o] = radius * (1/sqrt(K)) * sum_k cos(c*(w[o,k]-x[b,k])),  c = 2*pi/8
//          = radius * (1/sqrt(K)) * sum_k [cos(cx)cos(cw) + sin(cx)sin(cw)]
// B=2048, K=32768, O=10.
// Round 7: same MFMA structure as round 6 (verified), but 2 windows per
// iteration: 2 x-loads + 2 wtab-loads in flight per wave, 2 MFMAs, 16 iters.
// Doubles latency coverage (~1600 cy at 8 waves/SIMD vs ~900 cy HBM).

typedef _Float16 half2_t __attribute__((ext_vector_type(2)));
typedef _Float16 half8_t __attribute__((ext_vector_type(8)));
typedef float f32x4 __attribute__((ext_vector_type(4)));

#define K_DIM 32768
#define B_DIM 2048
#define O_DIM 10
#define NWIN 2048               // windows; one window = 16 x-ks = 32 K'-elems
#define KCH 64                  // K-chunks
#define WPC (NWIN / KCH)        // 32 windows per chunk
#define ITERS (WPC / 2)         // 16 iterations x 2 windows
#define MTILES (B_DIM / 64)     // 32 blocks of 64 rows
#define THREADS 256
#define INV_SQRT_K 0.005524271728019903f

// hardware v_sin/v_cos take REVOLUTIONS: sin(2*pi*r). c*x radians -> r = x/8.

__device__ __forceinline__ half2_t pack_cs(float c, float s) {
    return __builtin_bit_cast(half2_t, __builtin_amdgcn_cvt_pkrtz(c, s));
}

// A fragment from 4 consecutive x floats: (cos,sin) f16 pairs -> 8 f16
__device__ __forceinline__ half8_t afrag(float4 xc) {
    const float* xf = (const float*)&xc;
    uint4 au;
    unsigned u[4];
    #pragma unroll
    for (int j = 0; j < 4; ++j) {
        float rr = xf[j] * 0.125f;            // revolutions
        u[j] = __builtin_bit_cast(unsigned,
                   pack_cs(__builtin_amdgcn_cosf(rr),
                           __builtin_amdgcn_sinf(rr)));
    }
    au.x = u[0]; au.y = u[1]; au.z = u[2]; au.w = u[3];
    return __builtin_bit_cast(half8_t, au);
}

// B-fragment table: for window t, lane l: 16 bytes = (cos,sin) f16 pairs of
// w[o = l&15][k = t*16 + (l>>4)*4 + 0..3]; o >= 10 -> zeros.
__global__ void wtab_kernel(const float* __restrict__ w,
                            uint4* __restrict__ wtab) {
    int gid = blockIdx.x * THREADS + threadIdx.x;    // 2048*64 = 131072 exact
    int t = gid >> 6, l = gid & 63;
    int o = l & 15, kg = l >> 4;
    int k = t * 16 + kg * 4;
    uint4 v; v.x = v.y = v.z = v.w = 0u;
    if (o < O_DIM) {
        const float4 wv = *(const float4*)(w + (size_t)o * K_DIM + k);
        const float* wp = (const float*)&wv;
        unsigned u[4];
        #pragma unroll
        for (int j = 0; j < 4; ++j) {
            float rr = wp[j] * 0.125f;
            u[j] = __builtin_bit_cast(unsigned,
                       pack_cs(__builtin_amdgcn_cosf(rr),
                               __builtin_amdgcn_sinf(rr)));
        }
        v.x = u[0]; v.y = u[1]; v.z = u[2]; v.w = u[3];
    }
    wtab[gid] = v;
}

__global__ __launch_bounds__(THREADS) void gsim_mfma(
        const float* __restrict__ x,
        const uint4* __restrict__ wtab,
        float* __restrict__ part) {
    const int bid = blockIdx.x;
    const int mt = bid & (MTILES - 1);   // m-tile (fast) -> same-kc blocks adjacent
    const int kc = bid >> 5;             // k-chunk
    const int t = threadIdx.x;
    const int wave = t >> 6, lane = t & 63;
    const int o = lane & 15, kg = lane >> 4;

    // A-side: lane reads row (mt*64 + wave*16 + o), 4 floats per window
    const int row = mt * 64 + wave * 16 + o;
    const int t0 = kc * WPC;
    const float4* xp = (const float4*)x + ((size_t)row * (K_DIM / 4) + t0 * 4 + kg);
    const uint4* bp = wtab + (size_t)t0 * 64 + lane;

    f32x4 acc = {0.f, 0.f, 0.f, 0.f};

    // prologue: iteration 0's two windows
    float4 xc0 = xp[0], xc1 = xp[4];
    uint4  bc0 = bp[0], bc1 = bp[64];

    #pragma unroll 1
    for (int i = 0; i < ITERS; ++i) {
        const int ni = (i + 1 < ITERS) ? (i + 1) : i;  // last iter: harmless reload
        // issue next iteration's 4 loads; in flight across trig + 2 MFMAs
        float4 xn0 = xp[ni * 8],       xn1 = xp[ni * 8 + 4];
        uint4  bn0 = bp[ni * 128],     bn1 = bp[ni * 128 + 64];

        half8_t a0 = afrag(xc0);
        acc = __builtin_amdgcn_mfma_f32_16x16x32_f16(
                  a0, __builtin_bit_cast(half8_t, bc0), acc, 0, 0, 0);
        half8_t a1 = afrag(xc1);
        acc = __builtin_amdgcn_mfma_f32_16x16x32_f16(
                  a1, __builtin_bit_cast(half8_t, bc1), acc, 0, 0, 0);

        xc0 = xn0; xc1 = xn1; bc0 = bn0; bc1 = bn1;
    }

    // C/D layout: col = lane&15, row_in_tile = (lane>>4)*4 + reg  [m89]
    const int rbase = mt * 64 + wave * 16 + kg * 4;
    float* pp = part + ((size_t)kc * B_DIM + rbase) * 16 + o;
    #pragma unroll
    for (int reg = 0; reg < 4; ++reg)
        pp[(size_t)reg * 16] = acc[reg];
}

__global__ void finalize_kernel(const float* __restrict__ part,
                                const float* __restrict__ radius,
                                float* __restrict__ out) {
    int gid = blockIdx.x * THREADS + threadIdx.x;    // 2048*16 = 32768 exact
    int b = gid >> 4, o = gid & 15;
    if (o >= O_DIM) return;
    float s = 0.f;
    #pragma unroll 8
    for (int kc = 0; kc < KCH; ++kc)
        s += part[(size_t)kc * (B_DIM * 16) + gid];
    out[(size_t)b * O_DIM + o] = s * radius[0] * INV_SQRT_K;
}

extern "C" void kernel_launch(void* const* d_in, const int* in_sizes, int n_in,
                              void* d_out, int out_size, void* d_ws, size_t ws_size,
                              hipStream_t stream) {
    const float* x      = (const float*)d_in[0];
    const float* w      = (const float*)d_in[1];
    const float* radius = (const float*)d_in[2];
    float* out = (float*)d_out;

    // ws: wtab[2048][64] uint4 (2 MB) | part[64][2048][16] f32 (8 MB)
    uint4* wtab = (uint4*)d_ws;
    float* part = (float*)((char*)d_ws + (size_t)NWIN * 64 * 16);

    hipLaunchKernelGGL(wtab_kernel, dim3(NWIN * 64 / THREADS), dim3(THREADS),
                       0, stream, w, wtab);
    hipLaunchKernelGGL(gsim_mfma, dim3(MTILES * KCH), dim3(THREADS),
                       0, stream, x, wtab, part);
    hipLaunchKernelGGL(finalize_kernel, dim3(B_DIM * 16 / THREADS), dim3(THREADS),
                       0, stream, part, radius, out);
}